// Round 1
// baseline (373.433 us; speedup 1.0000x reference)
//
#include <hip/hip_runtime.h>
#include <hip/hip_bf16.h>
#include <stdint.h>

// Problem constants
#define B_ 2
#define T_ 2048
#define C_ 1024
#define H_ 16
#define D_ 64
// M = B*T = 4096 rows for both GEMMs

typedef __attribute__((ext_vector_type(8))) short bf16x8;
typedef __attribute__((ext_vector_type(4))) float f32x4;

__device__ __forceinline__ unsigned short f2bf(float f) {
  union { float f; uint32_t u; } c; c.f = f;
  uint32_t r = c.u + 0x7FFFu + ((c.u >> 16) & 1u);  // RNE
  return (unsigned short)(r >> 16);
}

// ---------------------------------------------------------------- cvt f32->bf16
__global__ void cvt_f32_bf16(const float* __restrict__ s,
                             unsigned short* __restrict__ d, int n4) {
  int i = blockIdx.x * blockDim.x + threadIdx.x;
  if (i >= n4) return;
  float4 v = ((const float4*)s)[i];
  ushort4 o;
  o.x = f2bf(v.x); o.y = f2bf(v.y); o.z = f2bf(v.z); o.w = f2bf(v.w);
  ((ushort4*)d)[i] = o;
}

// ---------------------------------------------------------------- mask lengths
// key_padding_mask is a prefix mask (arange(T) < len). Storage dtype of the
// bool array is harness-dependent; probe word 0 (token 0 is always valid):
//   int32 storage -> 1 ; uint8 storage -> 0x01010101 ; fp32 storage -> 0x3F800000
__global__ void compute_lengths(const unsigned int* __restrict__ mask,
                                int* __restrict__ lens) {
  int lane = threadIdx.x;
  unsigned int w0 = mask[0];
  for (int b = 0; b < B_; ++b) {
    int cnt = 0;
    if (w0 == 1u) {
      for (int t = lane; t < T_; t += 64) cnt += (mask[(size_t)b * T_ + t] != 0u);
    } else if (w0 == 0x3F800000u) {
      const float* mf = (const float*)mask;
      for (int t = lane; t < T_; t += 64) cnt += (mf[(size_t)b * T_ + t] != 0.f);
    } else {
      const unsigned char* mb = (const unsigned char*)mask;
      for (int t = lane; t < T_; t += 64) cnt += (mb[(size_t)b * T_ + t] != 0);
    }
    for (int off = 32; off > 0; off >>= 1) cnt += __shfl_down(cnt, off);
    if (lane == 0) lens[b] = cnt;
  }
}

// ---------------------------------------------------------------- GEMM (bt form)
// out[m][n] = sum_k A[m][k] * Bm[n][k] + bias[n]
// mode 0: scatter epilogue to Q/K/V (B,H,T,D) bf16 (Q scaled by 1/8)
// mode 1: fp32 output to outF (row-major M x N)
// Tile 128x128, BK=64, 4 waves (2x2), each wave 64x64 = 4x4 of 16x16 frags.
// LDS: row-major [128][64] bf16 (128 B rows) with XOR chunk swizzle:
//   physical 16B-chunk c of row holds logical k-chunk c ^ (row&7).
__global__ __launch_bounds__(256)
void gemm_bt(const unsigned short* __restrict__ A,
             const unsigned short* __restrict__ Bm,
             const float* __restrict__ bias,
             float* __restrict__ outF,
             unsigned short* __restrict__ Qw,
             unsigned short* __restrict__ Kw,
             unsigned short* __restrict__ Vw,
             int N, int K, int mode) {
  __shared__ unsigned short As[128 * 64];
  __shared__ unsigned short Bs[128 * 64];
  const int tid = threadIdx.x;
  const int lane = tid & 63;
  const int w = tid >> 6;
  const int wm = w >> 1, wn = w & 1;
  const int q4 = lane >> 4, l15 = lane & 15;
  const int bm = blockIdx.y * 128;
  const int bn = blockIdx.x * 128;

  f32x4 acc[4][4] = {};

  for (int kt = 0; kt < K; kt += 64) {
    // stage: each thread 4 chunks of A + 4 of B (16B each)
#pragma unroll
    for (int i = 0; i < 4; ++i) {
      int chunk = i * 256 + tid;      // 0..1023
      int row = chunk >> 3;           // 0..127
      int cc = chunk & 7;             // physical chunk in row
      int kc = cc ^ (row & 7);        // logical k-chunk stored there
      bf16x8 va = *(const bf16x8*)(A + (size_t)(bm + row) * K + kt + kc * 8);
      bf16x8 vb = *(const bf16x8*)(Bm + (size_t)(bn + row) * K + kt + kc * 8);
      *(bf16x8*)(As + (size_t)row * 64 + cc * 8) = va;
      *(bf16x8*)(Bs + (size_t)row * 64 + cc * 8) = vb;
    }
    __syncthreads();
#pragma unroll
    for (int kk = 0; kk < 2; ++kk) {
      bf16x8 af[4], bfv[4];
#pragma unroll
      for (int mi = 0; mi < 4; ++mi) {
        int row = wm * 64 + mi * 16 + l15;
        int pc = (kk * 4 + q4) ^ (row & 7);
        af[mi] = *(const bf16x8*)(As + (size_t)row * 64 + pc * 8);
      }
#pragma unroll
      for (int ni = 0; ni < 4; ++ni) {
        int row = wn * 64 + ni * 16 + l15;
        int pc = (kk * 4 + q4) ^ (row & 7);
        bfv[ni] = *(const bf16x8*)(Bs + (size_t)row * 64 + pc * 8);
      }
#pragma unroll
      for (int mi = 0; mi < 4; ++mi)
#pragma unroll
        for (int ni = 0; ni < 4; ++ni)
          acc[mi][ni] = __builtin_amdgcn_mfma_f32_16x16x32_bf16(
              af[mi], bfv[ni], acc[mi][ni], 0, 0, 0);
    }
    __syncthreads();
  }

  // epilogue; C/D frag: col = lane&15, row = (lane>>4)*4 + reg  [m89/m91]
#pragma unroll
  for (int mi = 0; mi < 4; ++mi) {
    const int row0 = bm + wm * 64 + mi * 16 + q4 * 4;
#pragma unroll
    for (int ni = 0; ni < 4; ++ni) {
      const int col = bn + wn * 64 + ni * 16 + l15;
      const float bv = bias[col];
#pragma unroll
      for (int r = 0; r < 4; ++r) {
        const int row = row0 + r;
        float v = acc[mi][ni][r] + bv;
        if (mode == 1) {
          outF[(size_t)row * N + col] = v;
        } else {
          int b = row >> 11, t = row & (T_ - 1);
          int which = col >> 10, c = col & (C_ - 1);
          int h = c >> 6, dd = c & (D_ - 1);
          unsigned short* dst = (which == 0) ? Qw : ((which == 1) ? Kw : Vw);
          if (which == 0) v *= 0.125f;  // fold softmax scale into Q
          dst[(((size_t)(b * H_ + h) * T_) + t) * D_ + dd] = f2bf(v);
        }
      }
    }
  }
}

// ---------------------------------------------------------------- V transpose
// V (BH, T, D) -> Vt (BH, D, T) so PV B-fragments are contiguous reads.
__global__ __launch_bounds__(256)
void transpose_v(const unsigned short* __restrict__ V,
                 unsigned short* __restrict__ Vt) {
  __shared__ unsigned short tile[64][65];
  int bh = blockIdx.y;
  int t0 = blockIdx.x * 64;
  int tid = threadIdx.x;
  int r = tid >> 2, c0 = (tid & 3) * 16;
  const uint4* s4 = (const uint4*)(V + ((size_t)bh * T_ + t0 + r) * D_ + c0);
  union { uint4 v; unsigned short u[8]; } ua, ub;
  ua.v = s4[0]; ub.v = s4[1];
#pragma unroll
  for (int j = 0; j < 8; ++j) {
    tile[r][c0 + j] = ua.u[j];
    tile[r][c0 + 8 + j] = ub.u[j];
  }
  __syncthreads();
  int dd = tid >> 2, tt0 = (tid & 3) * 16;
  union { uint4 v[2]; unsigned short u[16]; } ov;
#pragma unroll
  for (int j = 0; j < 16; ++j) ov.u[j] = tile[tt0 + j][dd];
  uint4* dptr = (uint4*)(Vt + ((size_t)bh * D_ + dd) * T_ + t0 + tt0);
  dptr[0] = ov.v[0];
  dptr[1] = ov.v[1];
}

// ---------------------------------------------------------------- attention
// One wave per (b,h,16 q-rows). K-tiles of 32. Q pre-scaled by 1/8.
// Online softmax; P goes D-frag -> LDS -> A-frag for PV.
__global__ __launch_bounds__(64)
void attn_fwd(const unsigned short* __restrict__ Qw,
              const unsigned short* __restrict__ Kw,
              const unsigned short* __restrict__ Vt,
              unsigned short* __restrict__ AO,
              const int* __restrict__ lens) {
  __shared__ unsigned short Pb[16 * 32];
  const int bh = blockIdx.y;
  const int b = bh >> 4;
  const int h = bh & 15;
  const int q0 = blockIdx.x * 16;
  const int lane = threadIdx.x;
  const int q4 = lane >> 4, l15 = lane & 15;
  const int len = lens[b];

  const unsigned short* Qp = Qw + (size_t)bh * T_ * D_;
  const unsigned short* Kp = Kw + (size_t)bh * T_ * D_;
  const unsigned short* Vp = Vt + (size_t)bh * D_ * T_;

  bf16x8 qf[2];
#pragma unroll
  for (int kk = 0; kk < 2; ++kk)
    qf[kk] = *(const bf16x8*)(Qp + (size_t)(q0 + l15) * D_ + kk * 32 + q4 * 8);

  f32x4 o[4] = {};
  float m[4], lsum[4];
#pragma unroll
  for (int r = 0; r < 4; ++r) { m[r] = -INFINITY; lsum[r] = 0.f; }

  int kcap = q0 + 15;
  if (kcap > len - 1) kcap = len - 1;  // keys beyond len are masked for all rows
  const int nkt = kcap / 32 + 1;

  for (int kt = 0; kt < nkt; ++kt) {
    const int kbase = kt * 32;
    // S = Q K^T (scaled): D-frags, row q_local=(q4*4+r), col = nt*16+l15
    f32x4 s[2];
#pragma unroll
    for (int nt = 0; nt < 2; ++nt) {
      f32x4 z = {};
#pragma unroll
      for (int kk = 0; kk < 2; ++kk) {
        bf16x8 kf = *(const bf16x8*)(Kp + (size_t)(kbase + nt * 16 + l15) * D_ +
                                     kk * 32 + q4 * 8);
        z = __builtin_amdgcn_mfma_f32_16x16x32_bf16(qf[kk], kf, z, 0, 0, 0);
      }
      s[nt] = z;
    }
    // mask + tile max
    float pmax[4];
#pragma unroll
    for (int r = 0; r < 4; ++r) pmax[r] = -INFINITY;
#pragma unroll
    for (int nt = 0; nt < 2; ++nt) {
      int kpos = kbase + nt * 16 + l15;
#pragma unroll
      for (int r = 0; r < 4; ++r) {
        int q = q0 + q4 * 4 + r;
        bool ok = (kpos <= q) && (kpos < len);
        float v = ok ? s[nt][r] : -INFINITY;
        s[nt][r] = v;
        pmax[r] = fmaxf(pmax[r], v);
      }
    }
#pragma unroll
    for (int r = 0; r < 4; ++r) {
      float v = pmax[r];
      v = fmaxf(v, __shfl_xor(v, 1));
      v = fmaxf(v, __shfl_xor(v, 2));
      v = fmaxf(v, __shfl_xor(v, 4));
      v = fmaxf(v, __shfl_xor(v, 8));
      pmax[r] = v;
    }
    float scale_o[4];
#pragma unroll
    for (int r = 0; r < 4; ++r) {
      float mn = fmaxf(m[r], pmax[r]);     // finite after tile 0 (k=0 always valid)
      scale_o[r] = __expf(m[r] - mn);
      m[r] = mn;
    }
    float psum[4] = {0.f, 0.f, 0.f, 0.f};
#pragma unroll
    for (int nt = 0; nt < 2; ++nt)
#pragma unroll
      for (int r = 0; r < 4; ++r) {
        float p = __expf(s[nt][r] - m[r]);  // masked: exp(-inf)=0
        psum[r] += p;
        Pb[(q4 * 4 + r) * 32 + nt * 16 + l15] = f2bf(p);
      }
#pragma unroll
    for (int r = 0; r < 4; ++r) {
      float v = psum[r];
      v += __shfl_xor(v, 1);
      v += __shfl_xor(v, 2);
      v += __shfl_xor(v, 4);
      v += __shfl_xor(v, 8);
      lsum[r] = lsum[r] * scale_o[r] + v;
    }
#pragma unroll
    for (int dt = 0; dt < 4; ++dt)
#pragma unroll
      for (int r = 0; r < 4; ++r) o[dt][r] *= scale_o[r];
    __syncthreads();
    bf16x8 pf = *(const bf16x8*)(Pb + l15 * 32 + q4 * 8);  // A-frag of P
#pragma unroll
    for (int dt = 0; dt < 4; ++dt) {
      bf16x8 vf = *(const bf16x8*)(Vp + (size_t)(dt * 16 + l15) * T_ + kbase + q4 * 8);
      o[dt] = __builtin_amdgcn_mfma_f32_16x16x32_bf16(pf, vf, o[dt], 0, 0, 0);
    }
    __syncthreads();
  }
  // epilogue: AO (B,T,C) bf16
#pragma unroll
  for (int r = 0; r < 4; ++r) {
    int q = q0 + q4 * 4 + r;
    float inv = 1.f / lsum[r];
#pragma unroll
    for (int dt = 0; dt < 4; ++dt) {
      AO[((size_t)(b * T_ + q)) * C_ + h * D_ + dt * 16 + l15] =
          f2bf(o[dt][r] * inv);
    }
  }
}

// ---------------------------------------------------------------- launch
extern "C" void kernel_launch(void* const* d_in, const int* in_sizes, int n_in,
                              void* d_out, int out_size, void* d_ws, size_t ws_size,
                              hipStream_t stream) {
  const float* x = (const float*)d_in[0];
  const unsigned int* mask = (const unsigned int*)d_in[1];
  const float* Wqkv = (const float*)d_in[2];
  const float* bqkv = (const float*)d_in[3];
  const float* Wproj = (const float*)d_in[4];
  const float* bproj = (const float*)d_in[5];
  float* out = (float*)d_out;

  unsigned short* XB = (unsigned short*)d_ws;       // x bf16       (4096x1024)
  unsigned short* WQ = XB + 4194304;                // Wqkv bf16    (3072x1024)
  unsigned short* WP = WQ + 3145728;                // Wproj bf16   (1024x1024)
  unsigned short* Qw = WP + 1048576;                // (B,H,T,D)
  unsigned short* Kw = Qw + 4194304;
  unsigned short* Vw = Kw + 4194304;
  unsigned short* Vt = Vw + 4194304;                // (B,H,D,T)
  unsigned short* AO = Vt + 4194304;                // attn out (B,T,C) bf16
  int* lens = (int*)(AO + 4194304);

  cvt_f32_bf16<<<4096, 256, 0, stream>>>(x, XB, 1048576);
  cvt_f32_bf16<<<3072, 256, 0, stream>>>(Wqkv, WQ, 786432);
  cvt_f32_bf16<<<1024, 256, 0, stream>>>(Wproj, WP, 262144);
  compute_lengths<<<1, 64, 0, stream>>>(mask, lens);

  // QKV projection: M=4096, N=3072, K=1024, scatter epilogue
  gemm_bt<<<dim3(3072 / 128, 4096 / 128), 256, 0, stream>>>(
      XB, WQ, bqkv, nullptr, Qw, Kw, Vw, 3072, 1024, 0);

  transpose_v<<<dim3(T_ / 64, B_ * H_), 256, 0, stream>>>(Vw, Vt);

  attn_fwd<<<dim3(T_ / 16, B_ * H_), 64, 0, stream>>>(Qw, Kw, Vt, AO, lens);

  // output projection: M=4096, N=1024, K=1024, fp32 out
  gemm_bt<<<dim3(1024 / 128, 4096 / 128), 256, 0, stream>>>(
      AO, WP, bproj, out, nullptr, nullptr, nullptr, 1024, 1024, 1);
}

// Round 4
// 298.600 us; speedup vs baseline: 1.2506x; 1.2506x over previous
//
#include <hip/hip_runtime.h>
#include <hip/hip_bf16.h>
#include <stdint.h>

// Problem constants
#define B_ 2
#define T_ 2048
#define C_ 1024
#define H_ 16
#define D_ 64
// M = B*T = 4096 rows for both GEMMs

typedef __attribute__((ext_vector_type(8))) short bf16x8;
typedef __attribute__((ext_vector_type(4))) float f32x4;

__device__ __forceinline__ unsigned short f2bf(float f) {
  union { float f; uint32_t u; } c; c.f = f;
  uint32_t r = c.u + 0x7FFFu + ((c.u >> 16) & 1u);  // RNE
  return (unsigned short)(r >> 16);
}

// ---------------------------------------------------------------- cvt f32->bf16
__global__ void cvt_f32_bf16(const float* __restrict__ s,
                             unsigned short* __restrict__ d, int n4) {
  int i = blockIdx.x * blockDim.x + threadIdx.x;
  if (i >= n4) return;
  float4 v = ((const float4*)s)[i];
  ushort4 o;
  o.x = f2bf(v.x); o.y = f2bf(v.y); o.z = f2bf(v.z); o.w = f2bf(v.w);
  ((ushort4*)d)[i] = o;
}

// ---------------------------------------------------------------- mask lengths
__global__ void compute_lengths(const unsigned int* __restrict__ mask,
                                int* __restrict__ lens) {
  int lane = threadIdx.x;
  unsigned int w0 = mask[0];
  for (int b = 0; b < B_; ++b) {
    int cnt = 0;
    if (w0 == 1u) {
      for (int t = lane; t < T_; t += 64) cnt += (mask[(size_t)b * T_ + t] != 0u);
    } else if (w0 == 0x3F800000u) {
      const float* mf = (const float*)mask;
      for (int t = lane; t < T_; t += 64) cnt += (mf[(size_t)b * T_ + t] != 0.f);
    } else {
      const unsigned char* mb = (const unsigned char*)mask;
      for (int t = lane; t < T_; t += 64) cnt += (mb[(size_t)b * T_ + t] != 0);
    }
    for (int off = 32; off > 0; off >>= 1) cnt += __shfl_down(cnt, off);
    if (lane == 0) lens[b] = cnt;
  }
}

// ---------------------------------------------------------------- GEMM (bt form)
// out[m][n] = sum_k A[m][k] * Bm[n][k] + bias[n]
// mode 0: scatter epilogue to Q/K/V (B,H,T,D) bf16 (Q scaled by 1/8)
// mode 1: fp32 output to outF (row-major M x N)
__global__ __launch_bounds__(256)
void gemm_bt(const unsigned short* __restrict__ A,
             const unsigned short* __restrict__ Bm,
             const float* __restrict__ bias,
             float* __restrict__ outF,
             unsigned short* __restrict__ Qw,
             unsigned short* __restrict__ Kw,
             unsigned short* __restrict__ Vw,
             int N, int K, int mode) {
  __shared__ unsigned short As[128 * 64];
  __shared__ unsigned short Bs[128 * 64];
  const int tid = threadIdx.x;
  const int lane = tid & 63;
  const int w = tid >> 6;
  const int wm = w >> 1, wn = w & 1;
  const int q4 = lane >> 4, l15 = lane & 15;
  const int bm = blockIdx.y * 128;
  const int bn = blockIdx.x * 128;

  f32x4 acc[4][4] = {};

  for (int kt = 0; kt < K; kt += 64) {
#pragma unroll
    for (int i = 0; i < 4; ++i) {
      int chunk = i * 256 + tid;      // 0..1023
      int row = chunk >> 3;           // 0..127
      int cc = chunk & 7;             // physical chunk in row
      int kc = cc ^ (row & 7);        // logical k-chunk stored there
      bf16x8 va = *(const bf16x8*)(A + (size_t)(bm + row) * K + kt + kc * 8);
      bf16x8 vb = *(const bf16x8*)(Bm + (size_t)(bn + row) * K + kt + kc * 8);
      *(bf16x8*)(As + (size_t)row * 64 + cc * 8) = va;
      *(bf16x8*)(Bs + (size_t)row * 64 + cc * 8) = vb;
    }
    __syncthreads();
#pragma unroll
    for (int kk = 0; kk < 2; ++kk) {
      bf16x8 af[4], bfv[4];
#pragma unroll
      for (int mi = 0; mi < 4; ++mi) {
        int row = wm * 64 + mi * 16 + l15;
        int pc = (kk * 4 + q4) ^ (row & 7);
        af[mi] = *(const bf16x8*)(As + (size_t)row * 64 + pc * 8);
      }
#pragma unroll
      for (int ni = 0; ni < 4; ++ni) {
        int row = wn * 64 + ni * 16 + l15;
        int pc = (kk * 4 + q4) ^ (row & 7);
        bfv[ni] = *(const bf16x8*)(Bs + (size_t)row * 64 + pc * 8);
      }
#pragma unroll
      for (int mi = 0; mi < 4; ++mi)
#pragma unroll
        for (int ni = 0; ni < 4; ++ni)
          acc[mi][ni] = __builtin_amdgcn_mfma_f32_16x16x32_bf16(
              af[mi], bfv[ni], acc[mi][ni], 0, 0, 0);
    }
    __syncthreads();
  }

  // epilogue; C/D frag: col = lane&15, row = (lane>>4)*4 + reg  [m89/m91]
#pragma unroll
  for (int mi = 0; mi < 4; ++mi) {
    const int row0 = bm + wm * 64 + mi * 16 + q4 * 4;
#pragma unroll
    for (int ni = 0; ni < 4; ++ni) {
      const int col = bn + wn * 64 + ni * 16 + l15;
      const float bv = bias[col];
#pragma unroll
      for (int r = 0; r < 4; ++r) {
        const int row = row0 + r;
        float v = acc[mi][ni][r] + bv;
        if (mode == 1) {
          outF[(size_t)row * N + col] = v;
        } else {
          int b = row >> 11, t = row & (T_ - 1);
          int which = col >> 10, c = col & (C_ - 1);
          int h = c >> 6, dd = c & (D_ - 1);
          unsigned short* dst = (which == 0) ? Qw : ((which == 1) ? Kw : Vw);
          if (which == 0) v *= 0.125f;  // fold softmax scale into Q
          dst[(((size_t)(b * H_ + h) * T_) + t) * D_ + dd] = f2bf(v);
        }
      }
    }
  }
}

// ---------------------------------------------------------------- V transpose
// V (BH, T, D) -> Vt (BH, D, T) so PV B-fragments are contiguous reads.
__global__ __launch_bounds__(256)
void transpose_v(const unsigned short* __restrict__ V,
                 unsigned short* __restrict__ Vt) {
  __shared__ unsigned short tile[64][65];
  int bh = blockIdx.y;
  int t0 = blockIdx.x * 64;
  int tid = threadIdx.x;
  int r = tid >> 2, c0 = (tid & 3) * 16;
  const uint4* s4 = (const uint4*)(V + ((size_t)bh * T_ + t0 + r) * D_ + c0);
  union { uint4 v; unsigned short u[8]; } ua, ub;
  ua.v = s4[0]; ub.v = s4[1];
#pragma unroll
  for (int j = 0; j < 8; ++j) {
    tile[r][c0 + j] = ua.u[j];
    tile[r][c0 + 8 + j] = ub.u[j];
  }
  __syncthreads();
  int dd = tid >> 2, tt0 = (tid & 3) * 16;
  union { uint4 v[2]; unsigned short u[16]; } ov;
#pragma unroll
  for (int j = 0; j < 16; ++j) ov.u[j] = tile[tt0 + j][dd];
  uint4* dptr = (uint4*)(Vt + ((size_t)bh * D_ + dd) * T_ + t0 + tt0);
  dptr[0] = ov.v[0];
  dptr[1] = ov.v[1];
}

// ---------------------------------------------------------------- attention
// 4 waves/block. Block handles 128 q-rows of one (b,h); wave w owns 32 rows.
// K-tiles of 64. K and V^T tiles staged in LDS (double-buffered, XOR-swizzled),
// shared across waves. Async-split staging: global loads issued before compute,
// LDS writes after. Q pre-scaled by 1/8. Online softmax; P via per-wave LDS.
__global__ __launch_bounds__(256)
void attn_fwd(const unsigned short* __restrict__ Qw,
              const unsigned short* __restrict__ Kw,
              const unsigned short* __restrict__ Vt,
              unsigned short* __restrict__ AO,
              const int* __restrict__ lens) {
  __shared__ unsigned short Ks[2][64 * 64];   // [key 64][d 64] swizzled
  __shared__ unsigned short Vs[2][64 * 64];   // [d 64][key 64] swizzled
  __shared__ unsigned short Pb[4][32 * 64];   // per-wave P [q 32][key 64] swizzled

  const int bh = blockIdx.y;
  const int b = bh >> 4;
  const int h = bh & 15;
  const int qt = gridDim.x - 1 - blockIdx.x;   // heavy tiles dispatch first
  const int q0 = qt * 128;
  const int tid = threadIdx.x;
  const int lane = tid & 63;
  const int w = tid >> 6;
  const int q4 = lane >> 4, l15 = lane & 15;
  const int len = lens[b];

  const unsigned short* Qp = Qw + (size_t)bh * T_ * D_;
  const unsigned short* Kp = Kw + (size_t)bh * T_ * D_;
  const unsigned short* Vp = Vt + (size_t)bh * D_ * T_;
  unsigned short* Pw = &Pb[w][0];

  const int qw0 = q0 + w * 32;        // this wave's first q row
  const int qwmax = qw0 + 31;

  // Q as A-frags: qf[mi][kk] : lane holds Q[qw0+mi*16+l15][kk*32+q4*8 ..+8]
  bf16x8 qf[2][2];
#pragma unroll
  for (int mi = 0; mi < 2; ++mi)
#pragma unroll
    for (int kk = 0; kk < 2; ++kk)
      qf[mi][kk] = *(const bf16x8*)(Qp + (size_t)(qw0 + mi * 16 + l15) * D_ +
                                    kk * 32 + q4 * 8);

  f32x4 o[2][4] = {};
  float m[2][4], lsum[2][4];
#pragma unroll
  for (int mi = 0; mi < 2; ++mi)
#pragma unroll
    for (int r = 0; r < 4; ++r) { m[mi][r] = -INFINITY; lsum[mi][r] = 0.f; }

  int kcap = q0 + 127;
  if (kcap > len - 1) kcap = len - 1;
  const int nkt = kcap / 64 + 1;

  // ---- staging (256 threads cover K tile 512 chunks + V tile 512)
  // chunk layout: row = chunk>>3, physical cc = chunk&7, logical kc = cc^(row&7)
  uint4 kreg[2], vreg[2];
  int srow[2], scc[2], skc[2];
#pragma unroll
  for (int i = 0; i < 2; ++i) {
    int chunk = i * 256 + tid;
    srow[i] = chunk >> 3;
    scc[i] = chunk & 7;
    skc[i] = scc[i] ^ (srow[i] & 7);
  }

  // prologue: stage tile 0
  {
    const int kbase = 0;
#pragma unroll
    for (int i = 0; i < 2; ++i) {
      kreg[i] = *(const uint4*)(Kp + (size_t)(kbase + srow[i]) * D_ + skc[i] * 8);
      vreg[i] = *(const uint4*)(Vp + (size_t)srow[i] * T_ + kbase + skc[i] * 8);
    }
#pragma unroll
    for (int i = 0; i < 2; ++i) {
      *(uint4*)(&Ks[0][srow[i] * 64 + scc[i] * 8]) = kreg[i];
      *(uint4*)(&Vs[0][srow[i] * 64 + scc[i] * 8]) = vreg[i];
    }
  }
  __syncthreads();

  int cur = 0;
  for (int kt = 0; kt < nkt; ++kt) {
    const int kbase = kt * 64;
    const bool prefetch = (kt + 1 < nkt);
    if (prefetch) {
      const int kb2 = kbase + 64;
#pragma unroll
      for (int i = 0; i < 2; ++i) {
        kreg[i] = *(const uint4*)(Kp + (size_t)(kb2 + srow[i]) * D_ + skc[i] * 8);
        vreg[i] = *(const uint4*)(Vp + (size_t)srow[i] * T_ + kb2 + skc[i] * 8);
      }
    }

    if (kbase <= qwmax) {  // wave has at least one unmasked key this tile
      // ---- S = Q K^T : kfr[nt][kk] from LDS
      bf16x8 kfr[4][2];
#pragma unroll
      for (int nt = 0; nt < 4; ++nt)
#pragma unroll
        for (int kk = 0; kk < 2; ++kk) {
          int row = nt * 16 + l15;
          int pc = (kk * 4 + q4) ^ (row & 7);
          kfr[nt][kk] = *(const bf16x8*)(&Ks[cur][row * 64 + pc * 8]);
        }
      f32x4 s[2][4];
#pragma unroll
      for (int mi = 0; mi < 2; ++mi)
#pragma unroll
        for (int nt = 0; nt < 4; ++nt) {
          f32x4 z = {};
          z = __builtin_amdgcn_mfma_f32_16x16x32_bf16(qf[mi][0], kfr[nt][0], z, 0, 0, 0);
          z = __builtin_amdgcn_mfma_f32_16x16x32_bf16(qf[mi][1], kfr[nt][1], z, 0, 0, 0);
          s[mi][nt] = z;
        }
      // ---- mask + tile max
      float pmax[2][4];
#pragma unroll
      for (int mi = 0; mi < 2; ++mi)
#pragma unroll
        for (int r = 0; r < 4; ++r) pmax[mi][r] = -INFINITY;
#pragma unroll
      for (int nt = 0; nt < 4; ++nt) {
        int kpos = kbase + nt * 16 + l15;
        bool kvalid = (kpos < len);
#pragma unroll
        for (int mi = 0; mi < 2; ++mi)
#pragma unroll
          for (int r = 0; r < 4; ++r) {
            int q = qw0 + mi * 16 + q4 * 4 + r;
            bool ok = kvalid && (kpos <= q);
            float v = ok ? s[mi][nt][r] : -INFINITY;
            s[mi][nt][r] = v;
            pmax[mi][r] = fmaxf(pmax[mi][r], v);
          }
      }
#pragma unroll
      for (int mi = 0; mi < 2; ++mi)
#pragma unroll
        for (int r = 0; r < 4; ++r) {
          float v = pmax[mi][r];
          v = fmaxf(v, __shfl_xor(v, 1));
          v = fmaxf(v, __shfl_xor(v, 2));
          v = fmaxf(v, __shfl_xor(v, 4));
          v = fmaxf(v, __shfl_xor(v, 8));
          pmax[mi][r] = v;
        }
      float sc[2][4];
#pragma unroll
      for (int mi = 0; mi < 2; ++mi)
#pragma unroll
        for (int r = 0; r < 4; ++r) {
          float mn = fmaxf(m[mi][r], pmax[mi][r]);  // finite from tile 0 on
          sc[mi][r] = __expf(m[mi][r] - mn);
          m[mi][r] = mn;
        }
      // ---- P = exp(S - m), write to per-wave LDS (swizzled), accumulate psum
      float psum[2][4] = {};
#pragma unroll
      for (int nt = 0; nt < 4; ++nt) {
        int lc = nt * 2 + (l15 >> 3);
#pragma unroll
        for (int mi = 0; mi < 2; ++mi)
#pragma unroll
          for (int r = 0; r < 4; ++r) {
            float p = __expf(s[mi][nt][r] - m[mi][r]);  // masked -> 0
            psum[mi][r] += p;
            int row = mi * 16 + q4 * 4 + r;
            int pc = lc ^ (row & 7);
            Pw[row * 64 + pc * 8 + (l15 & 7)] = f2bf(p);
          }
      }
#pragma unroll
      for (int mi = 0; mi < 2; ++mi)
#pragma unroll
        for (int r = 0; r < 4; ++r) {
          float v = psum[mi][r];
          v += __shfl_xor(v, 1);
          v += __shfl_xor(v, 2);
          v += __shfl_xor(v, 4);
          v += __shfl_xor(v, 8);
          lsum[mi][r] = lsum[mi][r] * sc[mi][r] + v;
        }
#pragma unroll
      for (int mi = 0; mi < 2; ++mi)
#pragma unroll
        for (int dt = 0; dt < 4; ++dt)
#pragma unroll
          for (int r = 0; r < 4; ++r) o[mi][dt][r] *= sc[mi][r];
      // ---- PV : P A-frags (own-wave LDS), V B-frags (shared LDS)
      bf16x8 pf[2][2];
#pragma unroll
      for (int mi = 0; mi < 2; ++mi)
#pragma unroll
        for (int kk = 0; kk < 2; ++kk) {
          int row = mi * 16 + l15;
          int pc = (kk * 4 + q4) ^ (row & 7);
          pf[mi][kk] = *(const bf16x8*)(&Pw[row * 64 + pc * 8]);
        }
      bf16x8 vfr[4][2];
#pragma unroll
      for (int dt = 0; dt < 4; ++dt)
#pragma unroll
        for (int kk = 0; kk < 2; ++kk) {
          int row = dt * 16 + l15;
          int pc = (kk * 4 + q4) ^ (row & 7);
          vfr[dt][kk] = *(const bf16x8*)(&Vs[cur][row * 64 + pc * 8]);
        }
#pragma unroll
      for (int mi = 0; mi < 2; ++mi)
#pragma unroll
        for (int dt = 0; dt < 4; ++dt) {
          o[mi][dt] = __builtin_amdgcn_mfma_f32_16x16x32_bf16(
              pf[mi][0], vfr[dt][0], o[mi][dt], 0, 0, 0);
          o[mi][dt] = __builtin_amdgcn_mfma_f32_16x16x32_bf16(
              pf[mi][1], vfr[dt][1], o[mi][dt], 0, 0, 0);
        }
    }

    if (prefetch) {
      const int nb = cur ^ 1;
#pragma unroll
      for (int i = 0; i < 2; ++i) {
        *(uint4*)(&Ks[nb][srow[i] * 64 + scc[i] * 8]) = kreg[i];
        *(uint4*)(&Vs[nb][srow[i] * 64 + scc[i] * 8]) = vreg[i];
      }
    }
    __syncthreads();
    cur ^= 1;
  }

  // epilogue: AO (B,T,C) bf16
#pragma unroll
  for (int mi = 0; mi < 2; ++mi)
#pragma unroll
    for (int r = 0; r < 4; ++r) {
      int q = qw0 + mi * 16 + q4 * 4 + r;
      float inv = 1.f / lsum[mi][r];
#pragma unroll
      for (int dt = 0; dt < 4; ++dt) {
        AO[((size_t)(b * T_ + q)) * C_ + h * D_ + dt * 16 + l15] =
            f2bf(o[mi][dt][r] * inv);
      }
    }
}

// ---------------------------------------------------------------- launch
extern "C" void kernel_launch(void* const* d_in, const int* in_sizes, int n_in,
                              void* d_out, int out_size, void* d_ws, size_t ws_size,
                              hipStream_t stream) {
  const float* x = (const float*)d_in[0];
  const unsigned int* mask = (const unsigned int*)d_in[1];
  const float* Wqkv = (const float*)d_in[2];
  const float* bqkv = (const float*)d_in[3];
  const float* Wproj = (const float*)d_in[4];
  const float* bproj = (const float*)d_in[5];
  float* out = (float*)d_out;

  unsigned short* XB = (unsigned short*)d_ws;       // x bf16       (4096x1024)
  unsigned short* WQ = XB + 4194304;                // Wqkv bf16    (3072x1024)
  unsigned short* WP = WQ + 3145728;                // Wproj bf16   (1024x1024)
  unsigned short* Qw = WP + 1048576;                // (B,H,T,D)
  unsigned short* Kw = Qw + 4194304;
  unsigned short* Vw = Kw + 4194304;
  unsigned short* Vt = Vw + 4194304;                // (B,H,D,T)
  unsigned short* AO = Vt + 4194304;                // attn out (B,T,C) bf16
  int* lens = (int*)(AO + 4194304);

  cvt_f32_bf16<<<4096, 256, 0, stream>>>(x, XB, 1048576);
  cvt_f32_bf16<<<3072, 256, 0, stream>>>(Wqkv, WQ, 786432);
  cvt_f32_bf16<<<1024, 256, 0, stream>>>(Wproj, WP, 262144);
  compute_lengths<<<1, 64, 0, stream>>>(mask, lens);

  // QKV projection: M=4096, N=3072, K=1024, scatter epilogue
  gemm_bt<<<dim3(3072 / 128, 4096 / 128), 256, 0, stream>>>(
      XB, WQ, bqkv, nullptr, Qw, Kw, Vw, 3072, 1024, 0);

  transpose_v<<<dim3(T_ / 64, B_ * H_), 256, 0, stream>>>(Vw, Vt);

  attn_fwd<<<dim3(T_ / 128, B_ * H_), 256, 0, stream>>>(Qw, Kw, Vt, AO, lens);

  // output projection: M=4096, N=1024, K=1024, fp32 out
  gemm_bt<<<dim3(1024 / 128, 4096 / 128), 256, 0, stream>>>(
      AO, WP, bproj, out, nullptr, nullptr, nullptr, 1024, 1024, 1);
}

// Round 5
// 251.420 us; speedup vs baseline: 1.4853x; 1.1877x over previous
//
#include <hip/hip_runtime.h>
#include <hip/hip_bf16.h>
#include <stdint.h>

// Problem constants
#define B_ 2
#define T_ 2048
#define C_ 1024
#define H_ 16
#define D_ 64

typedef __attribute__((ext_vector_type(8))) short bf16x8;
typedef __attribute__((ext_vector_type(4))) float f32x4;

__device__ __forceinline__ unsigned short f2bf(float f) {
  union { float f; uint32_t u; } c; c.f = f;
  uint32_t r = c.u + 0x7FFFu + ((c.u >> 16) & 1u);  // RNE
  return (unsigned short)(r >> 16);
}

// v_cvt_pk_bf16_f32: D[15:0]=bf16(lo), D[31:16]=bf16(hi), RNE
__device__ __forceinline__ uint32_t pack_bf16x2(float lo, float hi) {
  uint32_t r;
  asm("v_cvt_pk_bf16_f32 %0, %1, %2" : "=v"(r) : "v"(lo), "v"(hi));
  return r;
}

// async global->LDS, 16B per lane; LDS dest = uniform base + lane*16 (linear)
__device__ __forceinline__ void gload_lds16(const unsigned short* g,
                                            unsigned short* l) {
  __builtin_amdgcn_global_load_lds(
      (const __attribute__((address_space(1))) void*)(g),
      (__attribute__((address_space(3))) void*)(l), 16, 0, 0);
}

// ---------------------------------------------------------------- cvt f32->bf16
__global__ void cvt_f32_bf16(const float* __restrict__ s,
                             unsigned short* __restrict__ d, int n4) {
  int i = blockIdx.x * blockDim.x + threadIdx.x;
  if (i >= n4) return;
  float4 v = ((const float4*)s)[i];
  ushort4 o;
  o.x = f2bf(v.x); o.y = f2bf(v.y); o.z = f2bf(v.z); o.w = f2bf(v.w);
  ((ushort4*)d)[i] = o;
}

// ---------------------------------------------------------------- mask lengths
__global__ void compute_lengths(const unsigned int* __restrict__ mask,
                                int* __restrict__ lens) {
  int lane = threadIdx.x;
  unsigned int w0 = mask[0];
  for (int b = 0; b < B_; ++b) {
    int cnt = 0;
    if (w0 == 1u) {
      for (int t = lane; t < T_; t += 64) cnt += (mask[(size_t)b * T_ + t] != 0u);
    } else if (w0 == 0x3F800000u) {
      const float* mf = (const float*)mask;
      for (int t = lane; t < T_; t += 64) cnt += (mf[(size_t)b * T_ + t] != 0.f);
    } else {
      const unsigned char* mb = (const unsigned char*)mask;
      for (int t = lane; t < T_; t += 64) cnt += (mb[(size_t)b * T_ + t] != 0);
    }
    for (int off = 32; off > 0; off >>= 1) cnt += __shfl_down(cnt, off);
    if (lane == 0) lens[b] = cnt;
  }
}

// ---------------------------------------------------------------- GEMM (bt form)
// out[m][n] = sum_k A[m][k] * Bm[n][k] + bias[n]
// mode 0: scatter epilogue to Q/K/V (B,H,T,D) bf16 (Q scaled by log2e/8)
// mode 1: fp32 output to outF (row-major M x N)
// Staging: global_load_lds width-16, linear LDS dest, source pre-swizzled:
//   LDS chunk (row, cc) holds logical k-chunk cc^(row&7)  (T2 swizzle)
__global__ __launch_bounds__(256)
void gemm_bt(const unsigned short* __restrict__ A,
             const unsigned short* __restrict__ Bm,
             const float* __restrict__ bias,
             float* __restrict__ outF,
             unsigned short* __restrict__ Qw,
             unsigned short* __restrict__ Kw,
             unsigned short* __restrict__ Vw,
             int N, int K, int mode) {
  __shared__ unsigned short As[128 * 64];
  __shared__ unsigned short Bs[128 * 64];
  const int tid = threadIdx.x;
  const int lane = tid & 63;
  const int w = tid >> 6;
  const int wm = w >> 1, wn = w & 1;
  const int q4 = lane >> 4, l15 = lane & 15;
  const int bm = blockIdx.y * 128;
  const int bn = blockIdx.x * 128;

  f32x4 acc[4][4] = {};

  for (int kt = 0; kt < K; kt += 64) {
    // wave w stages rows w*32 .. w*32+31 of A and B (8 rows / call)
#pragma unroll
    for (int i = 0; i < 4; ++i) {
      int r0 = w * 32 + i * 8;
      int row = r0 + (lane >> 3);
      int kc = (lane & 7) ^ (row & 7);
      gload_lds16(A + (size_t)(bm + row) * K + kt + kc * 8, &As[r0 * 64]);
      gload_lds16(Bm + (size_t)(bn + row) * K + kt + kc * 8, &Bs[r0 * 64]);
    }
    __syncthreads();
#pragma unroll
    for (int kk = 0; kk < 2; ++kk) {
      bf16x8 af[4], bfv[4];
#pragma unroll
      for (int mi = 0; mi < 4; ++mi) {
        int row = wm * 64 + mi * 16 + l15;
        int pc = (kk * 4 + q4) ^ (row & 7);
        af[mi] = *(const bf16x8*)(As + (size_t)row * 64 + pc * 8);
      }
#pragma unroll
      for (int ni = 0; ni < 4; ++ni) {
        int row = wn * 64 + ni * 16 + l15;
        int pc = (kk * 4 + q4) ^ (row & 7);
        bfv[ni] = *(const bf16x8*)(Bs + (size_t)row * 64 + pc * 8);
      }
#pragma unroll
      for (int mi = 0; mi < 4; ++mi)
#pragma unroll
        for (int ni = 0; ni < 4; ++ni)
          acc[mi][ni] = __builtin_amdgcn_mfma_f32_16x16x32_bf16(
              af[mi], bfv[ni], acc[mi][ni], 0, 0, 0);
    }
    __syncthreads();
  }

  // epilogue; C/D frag: col = lane&15, row = (lane>>4)*4 + reg  [m89/m91]
#pragma unroll
  for (int mi = 0; mi < 4; ++mi) {
    const int row0 = bm + wm * 64 + mi * 16 + q4 * 4;
#pragma unroll
    for (int ni = 0; ni < 4; ++ni) {
      const int col = bn + wn * 64 + ni * 16 + l15;
      const float bv = bias[col];
#pragma unroll
      for (int r = 0; r < 4; ++r) {
        const int row = row0 + r;
        float v = acc[mi][ni][r] + bv;
        if (mode == 1) {
          outF[(size_t)row * N + col] = v;
        } else {
          int b = row >> 11, t = row & (T_ - 1);
          int which = col >> 10, c = col & (C_ - 1);
          int h = c >> 6, dd = c & (D_ - 1);
          unsigned short* dst = (which == 0) ? Qw : ((which == 1) ? Kw : Vw);
          // fold softmax scale AND log2(e) into Q (attention uses exp2)
          if (which == 0) v *= 0.1803368801111243f;  // 0.125 * log2(e)
          dst[(((size_t)(b * H_ + h) * T_) + t) * D_ + dd] = f2bf(v);
        }
      }
    }
  }
}

// ---------------------------------------------------------------- V transpose
__global__ __launch_bounds__(256)
void transpose_v(const unsigned short* __restrict__ V,
                 unsigned short* __restrict__ Vt) {
  __shared__ unsigned short tile[64][65];
  int bh = blockIdx.y;
  int t0 = blockIdx.x * 64;
  int tid = threadIdx.x;
  int r = tid >> 2, c0 = (tid & 3) * 16;
  const uint4* s4 = (const uint4*)(V + ((size_t)bh * T_ + t0 + r) * D_ + c0);
  union { uint4 v; unsigned short u[8]; } ua, ub;
  ua.v = s4[0]; ub.v = s4[1];
#pragma unroll
  for (int j = 0; j < 8; ++j) {
    tile[r][c0 + j] = ua.u[j];
    tile[r][c0 + 8 + j] = ub.u[j];
  }
  __syncthreads();
  int dd = tid >> 2, tt0 = (tid & 3) * 16;
  union { uint4 v[2]; unsigned short u[16]; } ov;
#pragma unroll
  for (int j = 0; j < 16; ++j) ov.u[j] = tile[tt0 + j][dd];
  uint4* dptr = (uint4*)(Vt + ((size_t)bh * D_ + dd) * T_ + t0 + tt0);
  dptr[0] = ov.v[0];
  dptr[1] = ov.v[1];
}

// ---------------------------------------------------------------- attention
// 4 waves/block, wave owns 32 q-rows (QBLK=128), KV tiles of 64.
// Swapped-operand scheme: S^T = mfma(K, Q)  -> lane l15 = q-row, per-lane
// softmax stats (m, lsum scalars per mi); P packed via v_cvt_pk_bf16_f32 and
// written as b64 to per-wave LDS [q32][k64] (8B-chunk XOR swizzle);
// PV: O^T = mfma(V^T, P^T). K/V staged by global_load_lds (dbuf, 1 barrier).
// Q pre-scaled by 0.125*log2e; softmax in exp2 domain. Defer-max THR=8.
__global__ __launch_bounds__(256)
void attn_fwd(const unsigned short* __restrict__ Qw,
              const unsigned short* __restrict__ Kw,
              const unsigned short* __restrict__ Vt,
              unsigned short* __restrict__ AO,
              const int* __restrict__ lens) {
  __shared__ unsigned short Ks[2][64 * 64];   // [key 64][d 64] chunk-swizzled
  __shared__ unsigned short Vs[2][64 * 64];   // [d 64][key 64] chunk-swizzled
  __shared__ unsigned short Pb[4][32 * 64];   // per-wave P [q 32][k 64]

  const int bh = blockIdx.y;
  const int b = bh >> 4;
  const int h = bh & 15;
  const int qt = gridDim.x - 1 - blockIdx.x;   // heavy tiles first
  const int q0 = qt * 128;
  const int tid = threadIdx.x;
  const int lane = tid & 63;
  const int w = tid >> 6;
  const int q4 = lane >> 4, l15 = lane & 15;
  const int len = lens[b];

  const unsigned short* Qp = Qw + (size_t)bh * T_ * D_;
  const unsigned short* Kp = Kw + (size_t)bh * T_ * D_;
  const unsigned short* Vp = Vt + (size_t)bh * D_ * T_;
  unsigned short* Pw = &Pb[w][0];

  const int qw0 = q0 + w * 32;
  const int qwmax = qw0 + 31;

  // Q fragments (also serve as B-operand for swapped QK^T)
  bf16x8 qf[2][2];
#pragma unroll
  for (int mi = 0; mi < 2; ++mi)
#pragma unroll
    for (int kk = 0; kk < 2; ++kk)
      qf[mi][kk] = *(const bf16x8*)(Qp + (size_t)(qw0 + mi * 16 + l15) * D_ +
                                    kk * 32 + q4 * 8);

  f32x4 ot[2][4] = {};                 // O^T accum: [mi][dt], lane l15=q, row=d
  float m[2] = {-INFINITY, -INFINITY}; // per-lane row stats (row = mi*16+l15)
  float lsum[2] = {0.f, 0.f};

  int kcap = q0 + 127;
  if (kcap > len - 1) kcap = len - 1;
  const int nkt = kcap / 64 + 1;

  // staging: wave w stages rows w*16..w*16+15 of K and V tiles (8 rows/call)
  const int srow = lane >> 3;   // 0..7
  const int scc = lane & 7;

  // prologue: stage tile 0 into buf 0
#pragma unroll
  for (int i = 0; i < 2; ++i) {
    int r0 = w * 16 + i * 8;
    int rk = r0 + srow;
    int kc = scc ^ (rk & 7);
    gload_lds16(Kp + (size_t)rk * D_ + kc * 8, &Ks[0][r0 * 64]);
    gload_lds16(Vp + (size_t)rk * T_ + kc * 8, &Vs[0][r0 * 64]);
  }
  __syncthreads();

  int cur = 0;
  for (int kt = 0; kt < nkt; ++kt) {
    const int kbase = kt * 64;
    // prefetch next tile into back buffer (in flight during compute)
    if (kt + 1 < nkt) {
      const int kb2 = kbase + 64;
#pragma unroll
      for (int i = 0; i < 2; ++i) {
        int r0 = w * 16 + i * 8;
        int rk = r0 + srow;
        int kc = scc ^ (rk & 7);
        gload_lds16(Kp + (size_t)(kb2 + rk) * D_ + kc * 8, &Ks[cur ^ 1][r0 * 64]);
        gload_lds16(Vp + (size_t)rk * T_ + kb2 + kc * 8, &Vs[cur ^ 1][r0 * 64]);
      }
    }

    if (kbase <= qwmax) {
      // ---- S^T = K Q^T : st[nt][mi], lane: col=q=l15, row=k=q4*4+r
      bf16x8 kfr[4][2];
#pragma unroll
      for (int nt = 0; nt < 4; ++nt)
#pragma unroll
        for (int kk = 0; kk < 2; ++kk) {
          int row = nt * 16 + l15;
          int pc = (kk * 4 + q4) ^ (row & 7);
          kfr[nt][kk] = *(const bf16x8*)(&Ks[cur][row * 64 + pc * 8]);
        }
      f32x4 st[4][2];
#pragma unroll
      for (int nt = 0; nt < 4; ++nt)
#pragma unroll
        for (int mi = 0; mi < 2; ++mi) {
          f32x4 z = {};
          z = __builtin_amdgcn_mfma_f32_16x16x32_bf16(kfr[nt][0], qf[mi][0], z, 0, 0, 0);
          z = __builtin_amdgcn_mfma_f32_16x16x32_bf16(kfr[nt][1], qf[mi][1], z, 0, 0, 0);
          st[nt][mi] = z;
        }
      // ---- mask + per-row (per-lane) max
      float pmax[2] = {-INFINITY, -INFINITY};
#pragma unroll
      for (int nt = 0; nt < 4; ++nt)
#pragma unroll
        for (int mi = 0; mi < 2; ++mi) {
          int qq = qw0 + mi * 16 + l15;
#pragma unroll
          for (int r = 0; r < 4; ++r) {
            int kpos = kbase + nt * 16 + q4 * 4 + r;
            bool ok = (kpos < len) && (kpos <= qq);
            float v = ok ? st[nt][mi][r] : -INFINITY;
            st[nt][mi][r] = v;
            pmax[mi] = fmaxf(pmax[mi], v);
          }
        }
#pragma unroll
      for (int mi = 0; mi < 2; ++mi) {
        float v = pmax[mi];
        v = fmaxf(v, __shfl_xor(v, 16));
        v = fmaxf(v, __shfl_xor(v, 32));
        pmax[mi] = v;
      }
      // ---- defer-max rescale (THR=8 in log2 domain)
#pragma unroll
      for (int mi = 0; mi < 2; ++mi) {
        if (!__all(pmax[mi] <= m[mi] + 8.f)) {
          float mn = fmaxf(m[mi], pmax[mi]);
          float sc = exp2f(m[mi] - mn);
          m[mi] = mn;
          lsum[mi] *= sc;
#pragma unroll
          for (int dt = 0; dt < 4; ++dt)
#pragma unroll
            for (int r = 0; r < 4; ++r) ot[mi][dt][r] *= sc;
        }
      }
      // ---- P = exp2(S - m): pack pairs, accumulate psum, write b64 to LDS
      float psum[2] = {0.f, 0.f};
#pragma unroll
      for (int nt = 0; nt < 4; ++nt)
#pragma unroll
        for (int mi = 0; mi < 2; ++mi) {
          float p0 = exp2f(st[nt][mi][0] - m[mi]);
          float p1 = exp2f(st[nt][mi][1] - m[mi]);
          float p2 = exp2f(st[nt][mi][2] - m[mi]);
          float p3 = exp2f(st[nt][mi][3] - m[mi]);
          psum[mi] += (p0 + p1) + (p2 + p3);
          uint32_t w0 = pack_bf16x2(p0, p1);
          uint32_t w1 = pack_bf16x2(p2, p3);
          int row = mi * 16 + l15;
          int c = nt * 4 + q4;                    // 8B chunk (4 bf16), k=c*4
          int phys = c ^ ((l15 & 7) << 1);        // keeps even/odd pairs adjacent
          uint2 pr; pr.x = w0; pr.y = w1;
          *(uint2*)(&Pw[row * 64 + phys * 4]) = pr;
        }
#pragma unroll
      for (int mi = 0; mi < 2; ++mi) {
        float v = psum[mi];
        v += __shfl_xor(v, 16);
        v += __shfl_xor(v, 32);
        lsum[mi] += v;
      }
      // ---- PV: O^T += V^T P^T ; A=vfr (V^T), B=pt (P^T)
      bf16x8 vfr[4][2];
#pragma unroll
      for (int dt = 0; dt < 4; ++dt)
#pragma unroll
        for (int kk = 0; kk < 2; ++kk) {
          int row = dt * 16 + l15;
          int pc = (kk * 4 + q4) ^ (row & 7);
          vfr[dt][kk] = *(const bf16x8*)(&Vs[cur][row * 64 + pc * 8]);
        }
      bf16x8 pt[2][2];
#pragma unroll
      for (int mi = 0; mi < 2; ++mi)
#pragma unroll
        for (int kk = 0; kk < 2; ++kk) {
          int row = mi * 16 + l15;
          int c0 = kk * 8 + q4 * 2;               // even chunk, b128 = 2 chunks
          int phys = c0 ^ ((l15 & 7) << 1);
          pt[mi][kk] = *(const bf16x8*)(&Pw[row * 64 + phys * 4]);
        }
#pragma unroll
      for (int mi = 0; mi < 2; ++mi)
#pragma unroll
        for (int dt = 0; dt < 4; ++dt) {
          ot[mi][dt] = __builtin_amdgcn_mfma_f32_16x16x32_bf16(
              vfr[dt][0], pt[mi][0], ot[mi][dt], 0, 0, 0);
          ot[mi][dt] = __builtin_amdgcn_mfma_f32_16x16x32_bf16(
              vfr[dt][1], pt[mi][1], ot[mi][dt], 0, 0, 0);
        }
    }

    __syncthreads();   // drains prefetch (vmcnt0) + guards buffer reuse
    cur ^= 1;
  }

  // epilogue: O^T frag -> lane l15=q, d = dt*16 + q4*4 + r (4 consecutive)
#pragma unroll
  for (int mi = 0; mi < 2; ++mi) {
    float inv = 1.f / lsum[mi];
    int qq = qw0 + mi * 16 + l15;
#pragma unroll
    for (int dt = 0; dt < 4; ++dt) {
      uint2 pr;
      pr.x = pack_bf16x2(ot[mi][dt][0] * inv, ot[mi][dt][1] * inv);
      pr.y = pack_bf16x2(ot[mi][dt][2] * inv, ot[mi][dt][3] * inv);
      *(uint2*)(&AO[(size_t)(b * T_ + qq) * C_ + h * 64 + dt * 16 + q4 * 4]) = pr;
    }
  }
}

// ---------------------------------------------------------------- launch
extern "C" void kernel_launch(void* const* d_in, const int* in_sizes, int n_in,
                              void* d_out, int out_size, void* d_ws, size_t ws_size,
                              hipStream_t stream) {
  const float* x = (const float*)d_in[0];
  const unsigned int* mask = (const unsigned int*)d_in[1];
  const float* Wqkv = (const float*)d_in[2];
  const float* bqkv = (const float*)d_in[3];
  const float* Wproj = (const float*)d_in[4];
  const float* bproj = (const float*)d_in[5];
  float* out = (float*)d_out;

  unsigned short* XB = (unsigned short*)d_ws;       // x bf16       (4096x1024)
  unsigned short* WQ = XB + 4194304;                // Wqkv bf16    (3072x1024)
  unsigned short* WP = WQ + 3145728;                // Wproj bf16   (1024x1024)
  unsigned short* Qw = WP + 1048576;                // (B,H,T,D)
  unsigned short* Kw = Qw + 4194304;
  unsigned short* Vw = Kw + 4194304;
  unsigned short* Vt = Vw + 4194304;                // (B,H,D,T)
  unsigned short* AO = Vt + 4194304;                // attn out (B,T,C) bf16
  int* lens = (int*)(AO + 4194304);

  cvt_f32_bf16<<<4096, 256, 0, stream>>>(x, XB, 1048576);
  cvt_f32_bf16<<<3072, 256, 0, stream>>>(Wqkv, WQ, 786432);
  cvt_f32_bf16<<<1024, 256, 0, stream>>>(Wproj, WP, 262144);
  compute_lengths<<<1, 64, 0, stream>>>(mask, lens);

  // QKV projection: M=4096, N=3072, K=1024, scatter epilogue
  gemm_bt<<<dim3(3072 / 128, 4096 / 128), 256, 0, stream>>>(
      XB, WQ, bqkv, nullptr, Qw, Kw, Vw, 3072, 1024, 0);

  transpose_v<<<dim3(T_ / 64, B_ * H_), 256, 0, stream>>>(Vw, Vt);

  attn_fwd<<<dim3(T_ / 128, B_ * H_), 256, 0, stream>>>(Qw, Kw, Vt, AO, lens);

  // output projection: M=4096, N=1024, K=1024, fp32 out
  gemm_bt<<<dim3(1024 / 128, 4096 / 128), 256, 0, stream>>>(
      AO, WP, bproj, out, nullptr, nullptr, nullptr, 1024, 1024, 1);
}

// Round 6
// 232.283 us; speedup vs baseline: 1.6077x; 1.0824x over previous
//
#include <hip/hip_runtime.h>
#include <hip/hip_bf16.h>
#include <stdint.h>

// Problem constants
#define B_ 2
#define T_ 2048
#define C_ 1024
#define H_ 16
#define D_ 64

typedef __attribute__((ext_vector_type(8))) short bf16x8;
typedef __attribute__((ext_vector_type(4))) float f32x4;

__device__ __forceinline__ unsigned short f2bf(float f) {
  union { float f; uint32_t u; } c; c.f = f;
  uint32_t r = c.u + 0x7FFFu + ((c.u >> 16) & 1u);  // RNE
  return (unsigned short)(r >> 16);
}

// v_cvt_pk_bf16_f32: D[15:0]=bf16(lo), D[31:16]=bf16(hi), RNE
__device__ __forceinline__ uint32_t pack_bf16x2(float lo, float hi) {
  uint32_t r;
  asm("v_cvt_pk_bf16_f32 %0, %1, %2" : "=v"(r) : "v"(lo), "v"(hi));
  return r;
}

// async global->LDS, 16B per lane; LDS dest = uniform base + lane*16 (linear)
__device__ __forceinline__ void gload_lds16(const unsigned short* g,
                                            unsigned short* l) {
  __builtin_amdgcn_global_load_lds(
      (const __attribute__((address_space(1))) void*)(g),
      (__attribute__((address_space(3))) void*)(l), 16, 0, 0);
}

// ---------------------------------------------------------------- cvt f32->bf16
__global__ void cvt_f32_bf16(const float* __restrict__ s,
                             unsigned short* __restrict__ d, int n4) {
  int i = blockIdx.x * blockDim.x + threadIdx.x;
  if (i >= n4) return;
  float4 v = ((const float4*)s)[i];
  ushort4 o;
  o.x = f2bf(v.x); o.y = f2bf(v.y); o.z = f2bf(v.z); o.w = f2bf(v.w);
  ((ushort4*)d)[i] = o;
}

// ---------------------------------------------------------------- mask lengths
__global__ void compute_lengths(const unsigned int* __restrict__ mask,
                                int* __restrict__ lens) {
  int lane = threadIdx.x;
  unsigned int w0 = mask[0];
  for (int b = 0; b < B_; ++b) {
    int cnt = 0;
    if (w0 == 1u) {
      for (int t = lane; t < T_; t += 64) cnt += (mask[(size_t)b * T_ + t] != 0u);
    } else if (w0 == 0x3F800000u) {
      const float* mf = (const float*)mask;
      for (int t = lane; t < T_; t += 64) cnt += (mf[(size_t)b * T_ + t] != 0.f);
    } else {
      const unsigned char* mb = (const unsigned char*)mask;
      for (int t = lane; t < T_; t += 64) cnt += (mb[(size_t)b * T_ + t] != 0);
    }
    for (int off = 32; off > 0; off >>= 1) cnt += __shfl_down(cnt, off);
    if (lane == 0) lens[b] = cnt;
  }
}

// ---------------------------------------------------------------- GEMM (bt form)
// out[m][n] = sum_k A[m][k] * Bm[n][k] + bias[n]
// mode 0: scatter epilogue to Q/K/V (B,H,T,D) bf16 (Q scaled by log2e/8)
// mode 1: fp32 output to outF (row-major M x N)
// Staging: global_load_lds width-16, linear LDS dest, source pre-swizzled:
//   LDS chunk (row, cc) holds logical k-chunk cc^(row&7)  (T2 swizzle)
__global__ __launch_bounds__(256)
void gemm_bt(const unsigned short* __restrict__ A,
             const unsigned short* __restrict__ Bm,
             const float* __restrict__ bias,
             float* __restrict__ outF,
             unsigned short* __restrict__ Qw,
             unsigned short* __restrict__ Kw,
             unsigned short* __restrict__ Vw,
             int N, int K, int mode) {
  __shared__ unsigned short As[128 * 64];
  __shared__ unsigned short Bs[128 * 64];
  const int tid = threadIdx.x;
  const int lane = tid & 63;
  const int w = tid >> 6;
  const int wm = w >> 1, wn = w & 1;
  const int q4 = lane >> 4, l15 = lane & 15;
  const int bm = blockIdx.y * 128;
  const int bn = blockIdx.x * 128;

  f32x4 acc[4][4] = {};

  for (int kt = 0; kt < K; kt += 64) {
    // wave w stages rows w*32 .. w*32+31 of A and B (8 rows / call)
#pragma unroll
    for (int i = 0; i < 4; ++i) {
      int r0 = w * 32 + i * 8;
      int row = r0 + (lane >> 3);
      int kc = (lane & 7) ^ (row & 7);
      gload_lds16(A + (size_t)(bm + row) * K + kt + kc * 8, &As[r0 * 64]);
      gload_lds16(Bm + (size_t)(bn + row) * K + kt + kc * 8, &Bs[r0 * 64]);
    }
    __syncthreads();
#pragma unroll
    for (int kk = 0; kk < 2; ++kk) {
      bf16x8 af[4], bfv[4];
#pragma unroll
      for (int mi = 0; mi < 4; ++mi) {
        int row = wm * 64 + mi * 16 + l15;
        int pc = (kk * 4 + q4) ^ (row & 7);
        af[mi] = *(const bf16x8*)(As + (size_t)row * 64 + pc * 8);
      }
#pragma unroll
      for (int ni = 0; ni < 4; ++ni) {
        int row = wn * 64 + ni * 16 + l15;
        int pc = (kk * 4 + q4) ^ (row & 7);
        bfv[ni] = *(const bf16x8*)(Bs + (size_t)row * 64 + pc * 8);
      }
#pragma unroll
      for (int mi = 0; mi < 4; ++mi)
#pragma unroll
        for (int ni = 0; ni < 4; ++ni)
          acc[mi][ni] = __builtin_amdgcn_mfma_f32_16x16x32_bf16(
              af[mi], bfv[ni], acc[mi][ni], 0, 0, 0);
    }
    __syncthreads();
  }

  // epilogue; C/D frag: col = lane&15, row = (lane>>4)*4 + reg  [m89/m91]
#pragma unroll
  for (int mi = 0; mi < 4; ++mi) {
    const int row0 = bm + wm * 64 + mi * 16 + q4 * 4;
#pragma unroll
    for (int ni = 0; ni < 4; ++ni) {
      const int col = bn + wn * 64 + ni * 16 + l15;
      const float bv = bias[col];
#pragma unroll
      for (int r = 0; r < 4; ++r) {
        const int row = row0 + r;
        float v = acc[mi][ni][r] + bv;
        if (mode == 1) {
          outF[(size_t)row * N + col] = v;
        } else {
          int b = row >> 11, t = row & (T_ - 1);
          int which = col >> 10, c = col & (C_ - 1);
          int h = c >> 6, dd = c & (D_ - 1);
          unsigned short* dst = (which == 0) ? Qw : ((which == 1) ? Kw : Vw);
          // fold softmax scale AND log2(e) into Q (attention uses exp2)
          if (which == 0) v *= 0.1803368801111243f;  // 0.125 * log2(e)
          dst[(((size_t)(b * H_ + h) * T_) + t) * D_ + dd] = f2bf(v);
        }
      }
    }
  }
}

// ---------------------------------------------------------------- V transpose
__global__ __launch_bounds__(256)
void transpose_v(const unsigned short* __restrict__ V,
                 unsigned short* __restrict__ Vt) {
  __shared__ unsigned short tile[64][65];
  int bh = blockIdx.y;
  int t0 = blockIdx.x * 64;
  int tid = threadIdx.x;
  int r = tid >> 2, c0 = (tid & 3) * 16;
  const uint4* s4 = (const uint4*)(V + ((size_t)bh * T_ + t0 + r) * D_ + c0);
  union { uint4 v; unsigned short u[8]; } ua, ub;
  ua.v = s4[0]; ub.v = s4[1];
#pragma unroll
  for (int j = 0; j < 8; ++j) {
    tile[r][c0 + j] = ua.u[j];
    tile[r][c0 + 8 + j] = ub.u[j];
  }
  __syncthreads();
  int dd = tid >> 2, tt0 = (tid & 3) * 16;
  union { uint4 v[2]; unsigned short u[16]; } ov;
#pragma unroll
  for (int j = 0; j < 16; ++j) ov.u[j] = tile[tt0 + j][dd];
  uint4* dptr = (uint4*)(Vt + ((size_t)bh * D_ + dd) * T_ + t0 + tt0);
  dptr[0] = ov.v[0];
  dptr[1] = ov.v[1];
}

// ---------------------------------------------------------------- attention
// 8 waves/block, wave owns 16 q-rows (QBLK=128), KV tiles of 64.
// Rationale: attn is latency-bound; 16 q/wave doubles wave count (4096 waves
// = 50% occupancy ceiling vs 25% at 32 q/wave) with IDENTICAL K/V HBM+LDS
// traffic (block q-extent unchanged; staging shared by all 8 waves).
// Swapped-operand: S^T = mfma(K,Q), lane l15 = q-row, per-lane softmax stats;
// P packed via v_cvt_pk_bf16_f32, b64 writes to per-wave LDS; O^T = mfma(Vt,Pt).
// K/V staged by global_load_lds (dbuf, 1 barrier/tile). Q pre-scaled by
// 0.125*log2e; exp2 domain; defer-max THR=8; interior tiles skip mask VALU.
__global__ __launch_bounds__(512)
void attn_fwd(const unsigned short* __restrict__ Qw,
              const unsigned short* __restrict__ Kw,
              const unsigned short* __restrict__ Vt,
              unsigned short* __restrict__ AO,
              const int* __restrict__ lens) {
  __shared__ unsigned short Ks[2][64 * 64];   // [key 64][d 64] chunk-swizzled
  __shared__ unsigned short Vs[2][64 * 64];   // [d 64][key 64] chunk-swizzled
  __shared__ unsigned short Pb[8][16 * 64];   // per-wave P [q 16][k 64]

  const int bh = blockIdx.y;
  const int b = bh >> 4;
  const int h = bh & 15;
  const int qt = gridDim.x - 1 - blockIdx.x;   // heavy tiles first
  const int q0 = qt * 128;
  const int tid = threadIdx.x;
  const int lane = tid & 63;
  const int w = tid >> 6;                      // 0..7
  const int q4 = lane >> 4, l15 = lane & 15;
  const int len = lens[b];

  const unsigned short* Qp = Qw + (size_t)bh * T_ * D_;
  const unsigned short* Kp = Kw + (size_t)bh * T_ * D_;
  const unsigned short* Vp = Vt + (size_t)bh * D_ * T_;
  unsigned short* Pw = &Pb[w][0];

  const int qw0 = q0 + w * 16;        // this wave's 16 q-rows
  const int qwmax = qw0 + 15;

  // Q fragments (B-operand for swapped QK^T): lane l15 = q-row
  bf16x8 qf[2];
#pragma unroll
  for (int kk = 0; kk < 2; ++kk)
    qf[kk] = *(const bf16x8*)(Qp + (size_t)(qw0 + l15) * D_ + kk * 32 + q4 * 8);

  f32x4 ot[4] = {};                 // O^T accum: [dt], lane l15=q, row=d
  float m = -INFINITY;              // per-lane (q-row) stats
  float lsum = 0.f;

  int kcap = q0 + 127;
  if (kcap > len - 1) kcap = len - 1;
  const int nkt = kcap / 64 + 1;

  // staging: wave w stages rows w*8..w*8+7 of K and V tiles (one call each)
  const int srow = lane >> 3;   // 0..7
  const int scc = lane & 7;
  const int sr0 = w * 8;
  const int rk = sr0 + srow;
  const int skc = scc ^ (rk & 7);

  // prologue: stage tile 0 into buf 0
  gload_lds16(Kp + (size_t)rk * D_ + skc * 8, &Ks[0][sr0 * 64]);
  gload_lds16(Vp + (size_t)rk * T_ + skc * 8, &Vs[0][sr0 * 64]);
  __syncthreads();

  int cur = 0;
  for (int kt = 0; kt < nkt; ++kt) {
    const int kbase = kt * 64;
    // prefetch next tile into back buffer (in flight during compute)
    if (kt + 1 < nkt) {
      const int kb2 = kbase + 64;
      gload_lds16(Kp + (size_t)(kb2 + rk) * D_ + skc * 8, &Ks[cur ^ 1][sr0 * 64]);
      gload_lds16(Vp + (size_t)rk * T_ + kb2 + skc * 8, &Vs[cur ^ 1][sr0 * 64]);
    }

    if (kbase <= qwmax) {
      // ---- S^T = K Q^T : st[nt], lane: col=q=l15, row=k=nt*16+q4*4+r
      f32x4 st[4];
#pragma unroll
      for (int nt = 0; nt < 4; ++nt) {
        bf16x8 kfr0, kfr1;
        {
          int row = nt * 16 + l15;
          int pc0 = q4 ^ (row & 7);
          int pc1 = (4 + q4) ^ (row & 7);
          kfr0 = *(const bf16x8*)(&Ks[cur][row * 64 + pc0 * 8]);
          kfr1 = *(const bf16x8*)(&Ks[cur][row * 64 + pc1 * 8]);
        }
        f32x4 z = {};
        z = __builtin_amdgcn_mfma_f32_16x16x32_bf16(kfr0, qf[0], z, 0, 0, 0);
        z = __builtin_amdgcn_mfma_f32_16x16x32_bf16(kfr1, qf[1], z, 0, 0, 0);
        st[nt] = z;
      }
      // ---- mask + per-row (per-lane) max
      const bool interior = (kbase + 63 <= qw0) && (kbase + 63 < len);
      float pmax = -INFINITY;
      if (interior) {
#pragma unroll
        for (int nt = 0; nt < 4; ++nt)
#pragma unroll
          for (int r = 0; r < 4; ++r) pmax = fmaxf(pmax, st[nt][r]);
      } else {
        const int qq = qw0 + l15;
#pragma unroll
        for (int nt = 0; nt < 4; ++nt)
#pragma unroll
          for (int r = 0; r < 4; ++r) {
            int kpos = kbase + nt * 16 + q4 * 4 + r;
            bool ok = (kpos < len) && (kpos <= qq);
            float v = ok ? st[nt][r] : -INFINITY;
            st[nt][r] = v;
            pmax = fmaxf(pmax, v);
          }
      }
      pmax = fmaxf(pmax, __shfl_xor(pmax, 16));
      pmax = fmaxf(pmax, __shfl_xor(pmax, 32));
      // ---- defer-max rescale (THR=8 in log2 domain)
      if (!__all(pmax <= m + 8.f)) {
        float mn = fmaxf(m, pmax);
        float sc = exp2f(m - mn);
        m = mn;
        lsum *= sc;
#pragma unroll
        for (int dt = 0; dt < 4; ++dt)
#pragma unroll
          for (int r = 0; r < 4; ++r) ot[dt][r] *= sc;
      }
      // ---- P = exp2(S - m): pack pairs, accumulate psum, write b64 to LDS
      float psum = 0.f;
#pragma unroll
      for (int nt = 0; nt < 4; ++nt) {
        float p0 = exp2f(st[nt][0] - m);
        float p1 = exp2f(st[nt][1] - m);
        float p2 = exp2f(st[nt][2] - m);
        float p3 = exp2f(st[nt][3] - m);
        psum += (p0 + p1) + (p2 + p3);
        uint32_t w0 = pack_bf16x2(p0, p1);
        uint32_t w1 = pack_bf16x2(p2, p3);
        int c = nt * 4 + q4;                    // 8B chunk (4 bf16), k=c*4
        int phys = c ^ ((l15 & 7) << 1);        // keeps pairs adjacent
        uint2 pr; pr.x = w0; pr.y = w1;
        *(uint2*)(&Pw[l15 * 64 + phys * 4]) = pr;
      }
      psum += __shfl_xor(psum, 16);
      psum += __shfl_xor(psum, 32);
      lsum += psum;
      // ---- PV: O^T += V^T P^T ; A=vfr (V^T, shared LDS), B=pt (P^T)
      bf16x8 pt[2];
#pragma unroll
      for (int kk = 0; kk < 2; ++kk) {
        int c0 = kk * 8 + q4 * 2;               // even chunk, b128 = 2 chunks
        int phys = c0 ^ ((l15 & 7) << 1);
        pt[kk] = *(const bf16x8*)(&Pw[l15 * 64 + phys * 4]);
      }
#pragma unroll
      for (int dt = 0; dt < 4; ++dt) {
        bf16x8 vfr0, vfr1;
        {
          int row = dt * 16 + l15;
          int pc0 = q4 ^ (row & 7);
          int pc1 = (4 + q4) ^ (row & 7);
          vfr0 = *(const bf16x8*)(&Vs[cur][row * 64 + pc0 * 8]);
          vfr1 = *(const bf16x8*)(&Vs[cur][row * 64 + pc1 * 8]);
        }
        ot[dt] = __builtin_amdgcn_mfma_f32_16x16x32_bf16(vfr0, pt[0], ot[dt], 0, 0, 0);
        ot[dt] = __builtin_amdgcn_mfma_f32_16x16x32_bf16(vfr1, pt[1], ot[dt], 0, 0, 0);
      }
    }

    __syncthreads();   // drains prefetch (vmcnt0) + guards buffer reuse
    cur ^= 1;
  }

  // epilogue: O^T frag -> lane l15=q, d = dt*16 + q4*4 + r (4 consecutive)
  {
    float inv = 1.f / lsum;
    int qq = qw0 + l15;
#pragma unroll
    for (int dt = 0; dt < 4; ++dt) {
      uint2 pr;
      pr.x = pack_bf16x2(ot[dt][0] * inv, ot[dt][1] * inv);
      pr.y = pack_bf16x2(ot[dt][2] * inv, ot[dt][3] * inv);
      *(uint2*)(&AO[(size_t)(b * T_ + qq) * C_ + h * 64 + dt * 16 + q4 * 4]) = pr;
    }
  }
}

// ---------------------------------------------------------------- launch
extern "C" void kernel_launch(void* const* d_in, const int* in_sizes, int n_in,
                              void* d_out, int out_size, void* d_ws, size_t ws_size,
                              hipStream_t stream) {
  const float* x = (const float*)d_in[0];
  const unsigned int* mask = (const unsigned int*)d_in[1];
  const float* Wqkv = (const float*)d_in[2];
  const float* bqkv = (const float*)d_in[3];
  const float* Wproj = (const float*)d_in[4];
  const float* bproj = (const float*)d_in[5];
  float* out = (float*)d_out;

  unsigned short* XB = (unsigned short*)d_ws;       // x bf16       (4096x1024)
  unsigned short* WQ = XB + 4194304;                // Wqkv bf16    (3072x1024)
  unsigned short* WP = WQ + 3145728;                // Wproj bf16   (1024x1024)
  unsigned short* Qw = WP + 1048576;                // (B,H,T,D)
  unsigned short* Kw = Qw + 4194304;
  unsigned short* Vw = Kw + 4194304;
  unsigned short* Vt = Vw + 4194304;                // (B,H,D,T)
  unsigned short* AO = Vt + 4194304;                // attn out (B,T,C) bf16
  int* lens = (int*)(AO + 4194304);

  cvt_f32_bf16<<<4096, 256, 0, stream>>>(x, XB, 1048576);
  cvt_f32_bf16<<<3072, 256, 0, stream>>>(Wqkv, WQ, 786432);
  cvt_f32_bf16<<<1024, 256, 0, stream>>>(Wproj, WP, 262144);
  compute_lengths<<<1, 64, 0, stream>>>(mask, lens);

  // QKV projection: M=4096, N=3072, K=1024, scatter epilogue
  gemm_bt<<<dim3(3072 / 128, 4096 / 128), 256, 0, stream>>>(
      XB, WQ, bqkv, nullptr, Qw, Kw, Vw, 3072, 1024, 0);

  transpose_v<<<dim3(T_ / 64, B_ * H_), 256, 0, stream>>>(Vw, Vt);

  attn_fwd<<<dim3(T_ / 128, B_ * H_), 512, 0, stream>>>(Qw, Kw, Vt, AO, lens);

  // output projection: M=4096, N=1024, K=1024, fp32 out
  gemm_bt<<<dim3(1024 / 128, 4096 / 128), 256, 0, stream>>>(
      AO, WP, bproj, out, nullptr, nullptr, nullptr, 1024, 1024, 1);
}